// Round 1
// baseline (107.212 us; speedup 1.0000x reference)
//
#include <hip/hip_runtime.h>
#include <hip/hip_bf16.h>

#define NN 8192
#define CC 64
#define KSPLIT 8
#define KCHUNK (NN / KSPLIT)   // 1024
#define BK 64
#define NSTEPS (KCHUNK / BK)   // 16

typedef __bf16 bf16;
typedef __bf16 bf16x8 __attribute__((ext_vector_type(8)));
typedef float f32x4 __attribute__((ext_vector_type(4)));
typedef unsigned short us8 __attribute__((ext_vector_type(8)));

// ---------------- kernel 1: softmax rows of Y -> Ys (f32), YsT (bf16, transposed), nwc partials
__global__ __launch_bounds__(256) void k1_softmax(const float* __restrict__ Yin,
                                                  float* __restrict__ Ys,
                                                  unsigned short* __restrict__ YsT,
                                                  float* __restrict__ nwc_part) {
    __shared__ float lds_t[64][65];   // [col][row_local], padded
    __shared__ float nwc_lds[4][64];
    const int t = threadIdx.x;
    const int w = t >> 6, lane = t & 63;
    const int b = blockIdx.x;
    const int r0 = b * 64;
    float nwc_acc = 0.f;
    for (int it = 0; it < 16; ++it) {
        const int rl = it * 4 + w;
        const int row = r0 + rl;
        float y = Yin[row * CC + lane];
        float mx = y;
        #pragma unroll
        for (int m = 32; m >= 1; m >>= 1) mx = fmaxf(mx, __shfl_xor(mx, m, 64));
        float e = __expf(y - mx);
        float s = e;
        #pragma unroll
        for (int m = 32; m >= 1; m >>= 1) s += __shfl_xor(s, m, 64);
        float ys = e / s;
        Ys[row * CC + lane] = ys;
        lds_t[lane][rl] = ys;
        nwc_acc += ys;
    }
    nwc_lds[w][lane] = nwc_acc;
    __syncthreads();
    if (t < 64)
        nwc_part[b * 64 + t] = nwc_lds[0][t] + nwc_lds[1][t] + nwc_lds[2][t] + nwc_lds[3][t];
    // write YsT bf16: thread t handles col c = t>>2, 16 rows starting q*16
    const int c = t >> 2, q = t & 3;
    unsigned short tmp[16];
    #pragma unroll
    for (int i = 0; i < 16; ++i) {
        float v = lds_t[c][q * 16 + i];
        tmp[i] = __builtin_bit_cast(unsigned short, (__bf16)v);
    }
    us8* dst = (us8*)(&YsT[(size_t)c * NN + r0 + q * 16]);
    dst[0] = *(us8*)(&tmp[0]);
    dst[1] = *(us8*)(&tmp[8]);
}

// ---------------- kernel 2: Bpart[kb] = A[:, kchunk] * Ys[kchunk, :]  (bf16 MFMA), + edge sums
__global__ __launch_bounds__(256) void k2_gemm(const float* __restrict__ A,
                                               const unsigned short* __restrict__ YsT,
                                               float* __restrict__ Bpart,
                                               float* __restrict__ edges_part) {
    // LDS: A tile 64x64 bf16 (swizzled) at [0,8192); YsT tile 64x64 bf16 (swizzled) at [8192,16384)
    __shared__ __align__(16) unsigned char lds[16384];
    __shared__ float ered[4];
    const int t = threadIdx.x;
    const int w = t >> 6, lane = t & 63;
    const int rb = blockIdx.x;   // 0..127 row block
    const int kb = blockIdx.y;   // 0..7   k split
    const int row0 = rb * 64;
    const int k0 = kb * KCHUNK;
    float esum = 0.f;
    f32x4 acc[4] = {};   // 4 col tiles of 16x16, rows w*16..w*16+16

    const int lq = lane >> 4;        // 0..3
    const int l15 = lane & 15;
    const int lrow = w * 16 + l15;   // A row within tile for A-fragment reads

    for (int s = 0; s < NSTEPS; ++s) {
        const int kbase = k0 + s * BK;
        __syncthreads();   // protect LDS from previous iteration's readers
        // --- stage A tile: 64 rows x 64 cols fp32 -> bf16, swizzled
        #pragma unroll
        for (int p = 0; p < 4; ++p) {
            const int idx = p * 256 + t;       // float4 index 0..1023
            const int r = idx >> 4;            // row 0..63
            const int c4 = idx & 15;           // float4 within row
            const float4 v = *(const float4*)(&A[(size_t)(row0 + r) * NN + kbase + c4 * 4]);
            esum += v.x + v.y + v.z + v.w;
            unsigned int lo = (unsigned int)__builtin_bit_cast(unsigned short, (__bf16)v.x)
                            | ((unsigned int)__builtin_bit_cast(unsigned short, (__bf16)v.y) << 16);
            unsigned int hi = (unsigned int)__builtin_bit_cast(unsigned short, (__bf16)v.z)
                            | ((unsigned int)__builtin_bit_cast(unsigned short, (__bf16)v.w) << 16);
            const int chunk = c4 >> 1;
            const int byteoff = r * 128 + (((chunk ^ (r & 7)) << 4)) + ((c4 & 1) << 3);
            *(uint2*)(&lds[byteoff]) = make_uint2(lo, hi);
        }
        // --- stage YsT tile: 64 cols x 64 k bf16 (already bf16), swizzled
        #pragma unroll
        for (int p = 0; p < 2; ++p) {
            const int cid = p * 256 + t;   // 16B-chunk id 0..511
            const int cc = cid >> 3;       // output col 0..63
            const int ch = cid & 7;        // chunk within row
            const float4 v = *(const float4*)(&YsT[(size_t)cc * NN + kbase + ch * 8]);
            *(float4*)(&lds[8192 + cc * 128 + (((ch ^ (cc & 7)) << 4))]) = v;
        }
        __syncthreads();
        // --- compute: 2 K-slices of 32, 4 col tiles
        #pragma unroll
        for (int kk = 0; kk < 2; ++kk) {
            const int chA = ((kk * 4 + lq) ^ (lrow & 7)) << 4;
            const bf16x8 a = *(const bf16x8*)(&lds[lrow * 128 + chA]);
            #pragma unroll
            for (int t4 = 0; t4 < 4; ++t4) {
                const int col = t4 * 16 + l15;
                const int chB = ((kk * 4 + lq) ^ (col & 7)) << 4;
                const bf16x8 bb = *(const bf16x8*)(&lds[8192 + col * 128 + chB]);
                acc[t4] = __builtin_amdgcn_mfma_f32_16x16x32_bf16(a, bb, acc[t4], 0, 0, 0);
            }
        }
    }
    // --- write partial B: Bpart[kb][row][col]
    const size_t base = ((size_t)kb * NN + row0) * CC;
    #pragma unroll
    for (int t4 = 0; t4 < 4; ++t4) {
        const int col = t4 * 16 + l15;
        #pragma unroll
        for (int r = 0; r < 4; ++r) {
            const int grow = w * 16 + lq * 4 + r;   // D layout: row=(lane>>4)*4+reg
            Bpart[base + (size_t)grow * CC + col] = acc[t4][r];
        }
    }
    // --- edge sum reduction (deterministic)
    #pragma unroll
    for (int m = 32; m >= 1; m >>= 1) esum += __shfl_xor(esum, m, 64);
    if (lane == 0) ered[w] = esum;
    __syncthreads();
    if (t == 0) edges_part[rb * KSPLIT + kb] = ered[0] + ered[1] + ered[2] + ered[3];
}

// ---------------- kernel 3: partial M over 64-row chunks: Mpart[b] = Ys[chunk]^T * B[chunk]
__global__ __launch_bounds__(256) void k3_mpart(const float* __restrict__ Bpart,
                                                const float* __restrict__ Ys,
                                                float* __restrict__ Mpart) {
    __shared__ float bl[4096];   // B rows [64][64]
    __shared__ float yl[4096];   // Ys rows [64][64]
    const int t = threadIdx.x;
    const int b = blockIdx.x;    // 0..127
    const int r0 = b * 64;
    for (int k = 0; k < 16; ++k) {
        const int e = k * 256 + t;
        const int i = e >> 6, c = e & 63;
        const size_t off = ((size_t)(r0 + i)) * CC + c;
        float s = 0.f;
        #pragma unroll
        for (int p = 0; p < KSPLIT; ++p) s += Bpart[(size_t)p * NN * CC + off];
        bl[e] = s;
        yl[e] = Ys[off];
    }
    __syncthreads();
    const int w = t >> 6, lane = t & 63;
    float acc[16];
    #pragma unroll
    for (int k = 0; k < 16; ++k) acc[k] = 0.f;
    for (int i = 0; i < 64; ++i) {
        const float bv = bl[i * 64 + lane];
        #pragma unroll
        for (int k = 0; k < 16; ++k)
            acc[k] += yl[i * 64 + 4 * k + w] * bv;   // c1 = 4k + w uniform per wave -> broadcast
    }
    #pragma unroll
    for (int k = 0; k < 16; ++k)
        Mpart[(size_t)b * 4096 + k * 256 + t] = acc[k];   // index == c1*64 + c2
}

// ---------------- kernel 4: reduce Mpart -> M[64][64]
__global__ __launch_bounds__(256) void k4_reduce(const float* __restrict__ Mpart,
                                                 float* __restrict__ M) {
    const int e = blockIdx.x * 256 + threadIdx.x;   // grid 16
    float s = 0.f;
    for (int b = 0; b < 128; ++b) s += Mpart[(size_t)b * 4096 + e];
    M[e] = s;
}

// ---------------- kernel 5: final scalar
__global__ __launch_bounds__(256) void k5_final(const float* __restrict__ M,
                                                const float* __restrict__ nwc_part,
                                                const float* __restrict__ edges_part,
                                                float* __restrict__ out) {
    __shared__ float red[256];
    const int t = threadIdx.x;
    float se = 0.f, st = 0.f, sc = 0.f;
    for (int i = t; i < 128 * KSPLIT; i += 256) se += edges_part[i];
    for (int e = t; e < 4096; e += 256) {
        const int c1 = e >> 6, c2 = e & 63;
        if (c2 > c1) st += M[e];
    }
    if (t < 64) {
        float nwc = 0.f;
        for (int b = 0; b < 128; ++b) nwc += nwc_part[b * 64 + t];
        const float me = (nwc * (nwc - 1.0f) + 1e-8f) * 0.5f;
        sc = M[t * 65] / me;
    }
    // three block reductions
    red[t] = se; __syncthreads();
    for (int s = 128; s >= 1; s >>= 1) { if (t < s) red[t] += red[t + s]; __syncthreads(); }
    const float tot_e = red[0]; __syncthreads();
    red[t] = st; __syncthreads();
    for (int s = 128; s >= 1; s >>= 1) { if (t < s) red[t] += red[t + s]; __syncthreads(); }
    const float tot_triu = red[0]; __syncthreads();
    red[t] = sc; __syncthreads();
    for (int s = 128; s >= 1; s >>= 1) { if (t < s) red[t] += red[t + s]; __syncthreads(); }
    const float cohesion = red[0];
    if (t == 0)
        out[0] = -cohesion + tot_triu / (tot_e + 1e-9f);
}

extern "C" void kernel_launch(void* const* d_in, const int* in_sizes, int n_in,
                              void* d_out, int out_size, void* d_ws, size_t ws_size,
                              hipStream_t stream) {
    const float* A   = (const float*)d_in[0];
    const float* Yin = (const float*)d_in[1];
    float* out = (float*)d_out;
    char* ws = (char*)d_ws;
    // workspace layout (bytes)
    float*          Ys         = (float*)(ws + 0);                  // 2 MB
    unsigned short* YsT        = (unsigned short*)(ws + 2097152);   // 1 MB
    float*          nwc_part   = (float*)(ws + 3145728);            // 32 KB
    float*          edges_part = (float*)(ws + 3178496);            // 4 KB
    float*          Bpart      = (float*)(ws + 4194304);            // 16 MB
    float*          Mpart      = (float*)(ws + 20971520);           // 2 MB
    float*          M          = (float*)(ws + 23068672);           // 16 KB

    k1_softmax<<<128, 256, 0, stream>>>(Yin, Ys, YsT, nwc_part);
    k2_gemm<<<dim3(128, KSPLIT), 256, 0, stream>>>(A, YsT, Bpart, edges_part);
    k3_mpart<<<128, 256, 0, stream>>>(Bpart, Ys, Mpart);
    k4_reduce<<<16, 256, 0, stream>>>(Mpart, M);
    k5_final<<<1, 256, 0, stream>>>(M, nwc_part, edges_part, out);
}